// Round 7
// baseline (207.863 us; speedup 1.0000x reference)
//
#include <hip/hip_runtime.h>
#include <cstdint>

// Problem constants (from setup_inputs: logits/targets [16,1,512,512] f32)
#define BB 16
#define HH 512
#define WW 512
#define NPIX (BB*HH*WW)          // 4194304
#define NROWS (BB*HH)            // 8192 (one block per image row)
#define WR (HH/32)               // 16 word-rows per image
#define NWORDS (BB*WR*WW)        // 131072 u32 = 512 KB
#define NXCD 8
#define CHUNK (NROWS/NXCD)       // 1024

// ---------------------------------------------------------------------------
// Kernel 0: vertical bit-pack of targets, 2 words per thread via float2 loads.
// vmask[b][w][j] bit r = (targets[b][32w+r][j] > 0.5).  512 KB total.
// 65536 threads (1024 waves, ~4/CU) so HBM latency is covered by TLP.
// ---------------------------------------------------------------------------
__global__ __launch_bounds__(256) void packbits(const float* __restrict__ targets,
                                                uint32_t* __restrict__ vmask) {
    const int flat = blockIdx.x * 256 + threadIdx.x;   // 0..65535
    const int jp = (flat & 255) * 2;                   // even column
    const int w  = (flat >> 8) & (WR - 1);
    const int b  = flat >> 12;
    const float2* base =
        (const float2*)(targets + ((size_t)(b * HH + w * 32)) * WW + jp);
    uint32_t w0 = 0, w1 = 0;
    #pragma unroll
    for (int r = 0; r < 32; ++r) {
        const float2 q = base[r * (WW / 2)];
        w0 |= (q.x > 0.5f ? 1u : 0u) << r;
        w1 |= (q.y > 0.5f ? 1u : 0u) << r;
    }
    ((uint2*)vmask)[flat] = make_uint2(w0, w1);        // 2*flat == b*8192+w*512+jp
}

// ---------------------------------------------------------------------------
// Fused kernel: one block per image row, 256 threads x 2 pixels each.
//  Phase 1: column distance to nearest OPPOSITE pixel via bitmask windows
//           (ffs/clz over +-32-row 64-bit windows; exact word-scan fallback).
//  Phase 2: packed (d<<1)|t in LDS; exact pruned row transform.
//  Phase 3: p = clip(sigmoid(logit)); block partial sum.
//  Tail:    last-block-done pattern folds the final reduction in.
// All distance math integer-exact. XCD swizzle keeps row locality per L2.
// ---------------------------------------------------------------------------
__global__ __launch_bounds__(256) void fused_row(
        const uint32_t* __restrict__ vmask,
        const float* __restrict__ logits,
        float* __restrict__ partial,
        uint32_t* __restrict__ counter,
        float* __restrict__ out) {
    const int bid = blockIdx.x;
    const int row = (bid & (NXCD - 1)) * CHUNK + (bid >> 3);  // bijective swizzle
    const int b   = row >> 9;
    const int i   = row & (HH - 1);
    const int j0  = threadIdx.x * 2;
    const int w   = i >> 5;
    const int p   = i & 31;

    __shared__ uint32_t pk_s[WW];
    __shared__ float    sw[4];
    __shared__ int      lastflag;

    const uint32_t* vm = vmask + (size_t)b * WR * WW;

    // early loads (all vectorized, overlap phase-1 math)
    const float2 x2 = *(const float2*)(logits + (size_t)row * WW + j0);
    const uint2  Ws = *(const uint2*)(vm + w * WW + j0);
    const uint2  Wu = (w > 0)      ? *(const uint2*)(vm + (w - 1) * WW + j0) : make_uint2(0u, 0u);
    const uint2  Wd = (w < WR - 1) ? *(const uint2*)(vm + (w + 1) * WW + j0) : make_uint2(0u, 0u);

    int dpx[2], tpx[2];
    #pragma unroll
    for (int q = 0; q < 2; ++q) {
        const int      j   = j0 + q;
        const uint32_t Wse = q ? Ws.y : Ws.x;
        const uint32_t Wup = q ? Wu.y : Wu.x;
        const uint32_t Wdn = q ? Wd.y : Wd.x;
        const int      t   = (int)((Wse >> p) & 1u);
        const uint32_t tm  = t ? 0xFFFFFFFFu : 0u;
        const uint32_t Xs  = Wse ^ tm;                          // 1 = opposite
        const uint32_t Xu  = (w > 0)      ? (Wup ^ tm) : 0u;
        const uint32_t Xd  = (w < WR - 1) ? (Wdn ^ tm) : 0u;

        // down window: bit q' = row i+1+q'  (covers rows i+1 .. 32w+63)
        const uint64_t Zd = ((uint64_t)Xs >> (p + 1)) | ((uint64_t)Xd << (31 - p));
        // up window: bit 63 = row i-1, descending (covers rows 32w-32 .. i-1)
        const uint64_t Zu = (((uint64_t)Xs << 32) | (uint64_t)Xu) << (32 - p);

        int dd, du;
        if (Zd) {
            dd = __ffsll((unsigned long long)Zd);               // 1-based == distance
        } else {                                                // essentially never
            dd = 1023;
            for (int ww = w + 2; ww < WR; ++ww) {
                const uint32_t Xw = vm[ww * WW + j] ^ tm;
                if (Xw) { dd = 32 * ww + (__ffs(Xw) - 1) - i; break; }
            }
        }
        if (Zu) {
            du = __clzll((long long)Zu) + 1;
        } else {                                                // essentially never
            du = 1023;
            for (int ww = w - 2; ww >= 0; --ww) {
                const uint32_t Xw = vm[ww * WW + j] ^ tm;
                if (Xw) { du = i - (32 * ww + 31 - __clz((int)Xw)); break; }
            }
        }
        dpx[q] = min(min(dd, du), 1023);
        tpx[q] = t;
    }

    *(uint2*)&pk_s[j0] = make_uint2((uint32_t)((dpx[0] << 1) | tpx[0]),
                                    (uint32_t)((dpx[1] << 1) | tpx[1]));
    __syncthreads();

    // ---- Phase 2 + 3 per pixel ----
    float v = 0.0f;
    #pragma unroll
    for (int q = 0; q < 2; ++q) {
        const int j = j0 + q;
        const int t = tpx[q];
        int m = dpx[q] * dpx[q];
        #pragma unroll
        for (int k = 1; k <= 2; ++k) {
            const int jl = j - k, jr = j + k;
            const uint32_t pl = pk_s[jl >= 0 ? jl : 0];
            const uint32_t pr = pk_s[jr < WW ? jr : (WW - 1)];
            const int dl = ((int)(pl & 1u) == t) ? (int)(pl >> 1) : 0;
            const int dr = ((int)(pr & 1u) == t) ? (int)(pr >> 1) : 0;
            const int cl = (jl >= 0) ? (dl * dl + k * k) : 0x7fffffff;
            const int cr = (jr < WW) ? (dr * dr + k * k) : 0x7fffffff;
            m = min(m, min(cl, cr));
        }
        {
            const int kmaxRow = max(j, WW - 1 - j);
            for (int k = 3; k <= kmaxRow && k * k < m; ++k) {
                const int k2 = k * k;
                if (k <= j) {
                    const uint32_t p2 = pk_s[j - k];
                    const int ddx = ((int)(p2 & 1u) == t) ? (int)(p2 >> 1) : 0;
                    const int c = ddx * ddx + k2;
                    m = c < m ? c : m;
                }
                if (k <= WW - 1 - j) {
                    const uint32_t p2 = pk_s[j + k];
                    const int ddx = ((int)(p2 & 1u) == t) ? (int)(p2 >> 1) : 0;
                    const int c = ddx * ddx + k2;
                    m = c < m ? c : m;
                }
            }
        }
        const float dt = __builtin_amdgcn_sqrtf((float)m);
        const float x  = q ? x2.y : x2.x;
        float pr = __builtin_amdgcn_rcpf(1.0f + __expf(-x));
        pr = fminf(fmaxf(pr, 1e-7f), (float)(1.0 - 1e-7));
        v += pr * dt;
    }

    // ---- block reduction (256 threads = 4 waves) ----
    #pragma unroll
    for (int off = 32; off > 0; off >>= 1)
        v += __shfl_down(v, off);

    const int lane = threadIdx.x & 63;
    const int wid  = threadIdx.x >> 6;
    if (lane == 0) sw[wid] = v;
    __syncthreads();
    if (threadIdx.x == 0) {
        const float s = (sw[0] + sw[1]) + (sw[2] + sw[3]);
        partial[row] = s;
        __threadfence();                       // release partial before signal
        const uint32_t old = atomicAdd(counter, 1u);
        lastflag = (old == NROWS - 1) ? 1 : 0;
    }
    __syncthreads();

    // ---- last-block-done final reduction ----
    if (lastflag) {
        __threadfence();                       // acquire: see all partials
        const float4* p4 = (const float4*)partial;
        float v2 = 0.0f;
        #pragma unroll
        for (int it = 0; it < NROWS / 4 / 256; ++it) {   // 8 iterations
            const float4 qq = p4[it * 256 + threadIdx.x];
            v2 += (qq.x + qq.y) + (qq.z + qq.w);
        }
        #pragma unroll
        for (int off = 32; off > 0; off >>= 1)
            v2 += __shfl_down(v2, off);
        if (lane == 0) sw[wid] = v2;
        __syncthreads();
        if (threadIdx.x == 0)
            out[0] = ((sw[0] + sw[1]) + (sw[2] + sw[3])) * (1.0f / (float)NPIX);
    }
}

extern "C" void kernel_launch(void* const* d_in, const int* in_sizes, int n_in,
                              void* d_out, int out_size, void* d_ws, size_t ws_size,
                              hipStream_t stream) {
    const float* logits  = (const float*)d_in[0];
    const float* targets = (const float*)d_in[1];
    float* out = (float*)d_out;

    // ws layout: [ vmask u32 NWORDS (512KB) | partial f32 NROWS (32KB) | counter u32 ]
    uint32_t* vmask   = (uint32_t*)d_ws;
    float*    partial = (float*)((char*)d_ws + (size_t)NWORDS * sizeof(uint32_t));
    uint32_t* counter = (uint32_t*)((char*)d_ws + (size_t)NWORDS * sizeof(uint32_t)
                                               + (size_t)NROWS * sizeof(float));

    hipMemsetAsync(counter, 0, sizeof(uint32_t), stream);
    packbits<<<NWORDS / 2 / 256, 256, 0, stream>>>(targets, vmask);
    fused_row<<<NROWS, 256, 0, stream>>>(vmask, logits, partial, counter, out);
}

// Round 8
// 28.679 us; speedup vs baseline: 7.2478x; 7.2478x over previous
//
#include <hip/hip_runtime.h>
#include <cstdint>

// Problem constants (from setup_inputs: logits/targets [16,1,512,512] f32)
#define BB 16
#define HH 512
#define WW 512
#define NPIX (BB*HH*WW)          // 4194304
#define NROWS (BB*HH)            // 8192 (one block per image row)
#define WR (HH/32)               // 16 word-rows per image
#define NWORDS (BB*WR*WW)        // 131072 u32 = 512 KB
#define NXCD 8
#define CHUNK (NROWS/NXCD)       // 1024

// ---------------------------------------------------------------------------
// Kernel 0: vertical bit-pack of targets, 2 words per thread via float2 loads.
// vmask[b][w][j] bit r = (targets[b][32w+r][j] > 0.5).  512 KB total.
// 65536 threads (1024 waves, ~4/CU) so HBM latency is covered by TLP.
// ---------------------------------------------------------------------------
__global__ __launch_bounds__(256) void packbits(const float* __restrict__ targets,
                                                uint32_t* __restrict__ vmask) {
    const int flat = blockIdx.x * 256 + threadIdx.x;   // 0..65535
    const int jp = (flat & 255) * 2;                   // even column
    const int w  = (flat >> 8) & (WR - 1);
    const int b  = flat >> 12;
    const float2* base =
        (const float2*)(targets + ((size_t)(b * HH + w * 32)) * WW + jp);
    uint32_t w0 = 0, w1 = 0;
    #pragma unroll
    for (int r = 0; r < 32; ++r) {
        const float2 q = base[r * (WW / 2)];
        w0 |= (q.x > 0.5f ? 1u : 0u) << r;
        w1 |= (q.y > 0.5f ? 1u : 0u) << r;
    }
    ((uint2*)vmask)[flat] = make_uint2(w0, w1);        // 2*flat == b*8192+w*512+jp
}

// ---------------------------------------------------------------------------
// Fused kernel: one block per image row, 512 threads = one pixel each.
// (Round-6 proven structure: 28.1 us total, absmax 0.0. No atomics/fences —
//  the round-7 last-block-done tail's device-scope threadfence/atomic chain
//  stalled all pipes: 204 us at VALUBusy 5%, HBM 0.5%.)
//  Phase 1: column distance to nearest OPPOSITE pixel via the bitmask:
//           3 u32 loads + ffs/clz on two 64-bit windows (covers +-32 rows
//           minimum); exact word-scan fallback beyond (P ~ 2^-32).
//  Phase 2: packed (d<<1)|t into LDS; exact pruned row transform.
//  Phase 3: p = clip(sigmoid(logit)); block-reduce sum of p*sqrt(dt2).
// All distance math integer-exact. XCD swizzle keeps row locality per L2.
// ---------------------------------------------------------------------------
__global__ __launch_bounds__(512) void fused_row(
        const uint32_t* __restrict__ vmask,
        const float* __restrict__ logits,
        float* __restrict__ partial) {
    const int bid = blockIdx.x;
    const int row = (bid & (NXCD - 1)) * CHUNK + (bid >> 3);  // bijective swizzle
    const int b   = row >> 9;          // image
    const int i   = row & (HH - 1);    // row within image
    const int j   = threadIdx.x;
    const int idx = row * WW + j;
    const int w   = i >> 5;
    const int p   = i & 31;

    __shared__ uint32_t pk_s[WW];
    __shared__ float    sw[8];

    const uint32_t* vm = vmask + (size_t)b * WR * WW;  // this image's mask

    // issue logits load early; overlaps phase 1
    const float x = logits[idx];

    const uint32_t Wself = vm[w * WW + j];
    const int      t     = (int)((Wself >> p) & 1u);
    const uint32_t tm    = t ? 0xFFFFFFFFu : 0u;

    const uint32_t Xs = Wself ^ tm;                                  // 1 = opposite
    const uint32_t Xu = (w > 0)      ? (vm[(w - 1) * WW + j] ^ tm) : 0u;
    const uint32_t Xd = (w < WR - 1) ? (vm[(w + 1) * WW + j] ^ tm) : 0u;

    // down window: bit q = row i+1+q  (covers rows i+1 .. 32w+63)
    const uint64_t Zd = ((uint64_t)Xs >> (p + 1)) | ((uint64_t)Xd << (31 - p));
    // up window: bit 63 = row i-1, descending (covers rows 32w-32 .. i-1)
    const uint64_t Zu = (((uint64_t)Xs << 32) | (uint64_t)Xu) << (32 - p);

    int dd, du;
    if (Zd) {
        dd = __ffsll((unsigned long long)Zd);          // 1-based == distance
    } else {                                           // essentially never
        dd = 1023;
        for (int ww = w + 2; ww < WR; ++ww) {
            const uint32_t Xw = vm[ww * WW + j] ^ tm;
            if (Xw) { dd = 32 * ww + (__ffs(Xw) - 1) - i; break; }
        }
    }
    if (Zu) {
        du = __clzll((long long)Zu) + 1;
    } else {                                           // essentially never
        du = 1023;
        for (int ww = w - 2; ww >= 0; --ww) {
            const uint32_t Xw = vm[ww * WW + j] ^ tm;
            if (Xw) { du = i - (32 * ww + 31 - __clz((int)Xw)); break; }
        }
    }
    const int d = min(min(dd, du), 1023);

    pk_s[j] = (uint32_t)((d << 1) | t);
    __syncthreads();

    // ---- Phase 2: row transform (exact pruned) ----
    int m = d * d;
    #pragma unroll
    for (int k = 1; k <= 2; ++k) {
        const int jl = j - k, jr = j + k;
        const uint32_t pl = pk_s[jl >= 0 ? jl : 0];
        const uint32_t pr = pk_s[jr < WW ? jr : (WW - 1)];
        const int dl = ((int)(pl & 1u) == t) ? (int)(pl >> 1) : 0;
        const int dr = ((int)(pr & 1u) == t) ? (int)(pr >> 1) : 0;
        const int cl = (jl >= 0) ? (dl * dl + k * k) : 0x7fffffff;
        const int cr = (jr < WW) ? (dr * dr + k * k) : 0x7fffffff;
        m = min(m, min(cl, cr));
    }
    {
        const int kmaxRow = max(j, WW - 1 - j);
        for (int k = 3; k <= kmaxRow && k * k < m; ++k) {
            const int k2 = k * k;
            if (k <= j) {
                const uint32_t p2 = pk_s[j - k];
                const int ddx = ((int)(p2 & 1u) == t) ? (int)(p2 >> 1) : 0;
                const int c = ddx * ddx + k2;
                m = c < m ? c : m;
            }
            if (k <= WW - 1 - j) {
                const uint32_t p2 = pk_s[j + k];
                const int ddx = ((int)(p2 & 1u) == t) ? (int)(p2 >> 1) : 0;
                const int c = ddx * ddx + k2;
                m = c < m ? c : m;
            }
        }
    }

    const float dt = sqrtf((float)m);

    // ---- Phase 3: loss term + block reduction ----
    float pr = 1.0f / (1.0f + __expf(-x));
    pr = fminf(fmaxf(pr, 1e-7f), (float)(1.0 - 1e-7));
    float v = pr * dt;

    #pragma unroll
    for (int off = 32; off > 0; off >>= 1)
        v += __shfl_down(v, off);

    const int lane = threadIdx.x & 63;
    const int wid  = threadIdx.x >> 6;
    if (lane == 0) sw[wid] = v;
    __syncthreads();
    if (threadIdx.x == 0) {
        float s = 0.0f;
        #pragma unroll
        for (int ww = 0; ww < 8; ++ww) s += sw[ww];
        partial[row] = s;
    }
}

// ---------------------------------------------------------------------------
// Deterministic final reduction of NROWS partials -> mean
// ---------------------------------------------------------------------------
__global__ __launch_bounds__(512) void finalreduce(
        const float* __restrict__ partial,
        float* __restrict__ out) {
    const float4* p4 = (const float4*)partial;
    float v = 0.0f;
    #pragma unroll
    for (int it = 0; it < NROWS / 4 / 512; ++it) {
        const float4 q = p4[it * 512 + threadIdx.x];
        v += (q.x + q.y) + (q.z + q.w);
    }

    #pragma unroll
    for (int off = 32; off > 0; off >>= 1)
        v += __shfl_down(v, off);

    __shared__ float sw[8];
    const int lane = threadIdx.x & 63;
    const int wid  = threadIdx.x >> 6;
    if (lane == 0) sw[wid] = v;
    __syncthreads();
    if (threadIdx.x == 0) {
        float s = 0.0f;
        #pragma unroll
        for (int ww = 0; ww < 8; ++ww) s += sw[ww];
        out[0] = s * (1.0f / (float)NPIX);
    }
}

extern "C" void kernel_launch(void* const* d_in, const int* in_sizes, int n_in,
                              void* d_out, int out_size, void* d_ws, size_t ws_size,
                              hipStream_t stream) {
    const float* logits  = (const float*)d_in[0];
    const float* targets = (const float*)d_in[1];
    float* out = (float*)d_out;

    // workspace layout: [ vmask u32 NWORDS (512KB) | partial float NROWS (32KB) ]
    uint32_t* vmask = (uint32_t*)d_ws;
    float* partial  = (float*)((char*)d_ws + (size_t)NWORDS * sizeof(uint32_t));

    packbits<<<NWORDS / 2 / 256, 256, 0, stream>>>(targets, vmask);
    fused_row<<<NROWS, 512, 0, stream>>>(vmask, logits, partial);
    finalreduce<<<1, 512, 0, stream>>>(partial, out);
}

// Round 11
// 22.068 us; speedup vs baseline: 9.4193x; 1.2996x over previous
//
#include <hip/hip_runtime.h>
#include <cstdint>

// Problem constants (from setup_inputs: logits/targets [16,1,512,512] f32)
#define BB 16
#define HH 512
#define WW 512
#define NPIX (BB*HH*WW)          // 4194304
#define WR (HH/32)               // 16 word-rows per image
#define NWORDS (BB*WR*WW)        // 131072 u32 = 512 KB
#define NXCD 8
#define RPB 4                    // rows per block
#define NGRP (BB*HH/RPB)         // 2048 blocks
#define GCHUNK (NGRP/NXCD)       // 256

// ---------------------------------------------------------------------------
// Kernel 0: vertical bit-pack of targets, 2 words per thread via float2 loads.
// vmask[b][w][j] bit r = (targets[b][32w+r][j] > 0.5).  512 KB total.
// ---------------------------------------------------------------------------
__global__ __launch_bounds__(256) void packbits(const float* __restrict__ targets,
                                                uint32_t* __restrict__ vmask) {
    const int flat = blockIdx.x * 256 + threadIdx.x;   // 0..65535
    const int jp = (flat & 255) * 2;                   // even column
    const int w  = (flat >> 8) & (WR - 1);
    const int b  = flat >> 12;
    const float2* base =
        (const float2*)(targets + ((size_t)(b * HH + w * 32)) * WW + jp);
    uint32_t w0 = 0, w1 = 0;
    #pragma unroll
    for (int r = 0; r < 32; ++r) {
        const float2 q = base[r * (WW / 2)];
        w0 |= (q.x > 0.5f ? 1u : 0u) << r;
        w1 |= (q.y > 0.5f ? 1u : 0u) << r;
    }
    ((uint2*)vmask)[flat] = make_uint2(w0, w1);        // 2*flat == b*8192+w*512+jp
}

// ---------------------------------------------------------------------------
// Fused kernel: one block per 4-ROW GROUP (4-aligned rows always share one
// 32-bit word-row), 512 threads = one column each, 4 pixels per thread.
//  Phase 1: the SAME 3 vmask words (self/up/down) serve all 4 rows; per row
//           just shift/ffs/clz on 64-bit windows (exact; word-scan fallback).
//  Phase 2: packed (d<<1)|t in LDS [4][512]; exact pruned row transform,
//           4 independent chains per thread -> 4-way ILP over LDS latency.
//  Phase 3: p = clip(sigmoid(logit)) via rcp; v += p*sqrt(m); one block
//           reduction per 2048 pixels.
// No atomics/fences (round-7 lesson: device-scope fence chain = 204 us).
// ---------------------------------------------------------------------------
__global__ __launch_bounds__(512) void fused_row4(
        const uint32_t* __restrict__ vmask,
        const float* __restrict__ logits,
        float* __restrict__ partial) {
    const int bid = blockIdx.x;
    const int g   = (bid & (NXCD - 1)) * GCHUNK + (bid >> 3);  // bijective swizzle
    const int b   = g >> 7;                 // 128 groups per image
    const int i0  = (g & 127) << 2;         // first row of the group
    const int j   = threadIdx.x;
    const int w   = i0 >> 5;                // shared word-row (i0..i0+3 same word)
    const int p0  = i0 & 31;

    __shared__ uint32_t pk_s[RPB][WW];
    __shared__ float    sw[8];

    const uint32_t* vm = vmask + (size_t)b * WR * WW;

    // one word-column triple serves all 4 rows
    const uint32_t Wse = vm[w * WW + j];
    const uint32_t Wup = (w > 0)      ? vm[(w - 1) * WW + j] : 0u;
    const uint32_t Wdn = (w < WR - 1) ? vm[(w + 1) * WW + j] : 0u;

    // logits for the 4 pixels (independent loads, overlap phase 1)
    float xs[RPB];
    #pragma unroll
    for (int r = 0; r < RPB; ++r)
        xs[r] = logits[((size_t)(b * HH + i0 + r)) * WW + j];

    int dpx[RPB], tpx[RPB];
    #pragma unroll
    for (int r = 0; r < RPB; ++r) {
        const int      p  = p0 + r;         // <= 31 always
        const int      i  = i0 + r;
        const int      t  = (int)((Wse >> p) & 1u);
        const uint32_t tm = t ? 0xFFFFFFFFu : 0u;
        const uint32_t Xs = Wse ^ tm;                              // 1 = opposite
        const uint32_t Xu = (w > 0)      ? (Wup ^ tm) : 0u;
        const uint32_t Xd = (w < WR - 1) ? (Wdn ^ tm) : 0u;

        // down window: bit q = row i+1+q (covers rows i+1 .. 32w+63)
        const uint64_t Zd = ((uint64_t)Xs >> (p + 1)) | ((uint64_t)Xd << (31 - p));
        // up window: bit 63 = row i-1, descending (covers rows 32w-32 .. i-1)
        const uint64_t Zu = (((uint64_t)Xs << 32) | (uint64_t)Xu) << (32 - p);

        int dd, du;
        if (Zd) {
            dd = __ffsll((unsigned long long)Zd);      // 1-based == distance
        } else {                                       // essentially never
            dd = 1023;
            for (int ww = w + 2; ww < WR; ++ww) {
                const uint32_t Xw = vm[ww * WW + j] ^ tm;
                if (Xw) { dd = 32 * ww + (__ffs(Xw) - 1) - i; break; }
            }
        }
        if (Zu) {
            du = __clzll((long long)Zu) + 1;
        } else {                                       // essentially never
            du = 1023;
            for (int ww = w - 2; ww >= 0; --ww) {
                const uint32_t Xw = vm[ww * WW + j] ^ tm;
                if (Xw) { du = i - (32 * ww + 31 - __clz((int)Xw)); break; }
            }
        }
        dpx[r] = min(min(dd, du), 1023);
        tpx[r] = t;
        pk_s[r][j] = (uint32_t)((dpx[r] << 1) | t);
    }
    __syncthreads();

    // ---- Phase 2 + 3: four independent row transforms (ILP) ----
    float v = 0.0f;
    #pragma unroll
    for (int r = 0; r < RPB; ++r) {
        const int t = tpx[r];
        int m = dpx[r] * dpx[r];
        #pragma unroll
        for (int k = 1; k <= 2; ++k) {
            const int jl = j - k, jr = j + k;
            const uint32_t pl = pk_s[r][jl >= 0 ? jl : 0];
            const uint32_t pr = pk_s[r][jr < WW ? jr : (WW - 1)];
            const int dl = ((int)(pl & 1u) == t) ? (int)(pl >> 1) : 0;
            const int dr = ((int)(pr & 1u) == t) ? (int)(pr >> 1) : 0;
            const int cl = (jl >= 0) ? (dl * dl + k * k) : 0x7fffffff;
            const int cr = (jr < WW) ? (dr * dr + k * k) : 0x7fffffff;
            m = min(m, min(cl, cr));
        }
        {
            const int kmaxRow = max(j, WW - 1 - j);
            for (int k = 3; k <= kmaxRow && k * k < m; ++k) {
                const int k2 = k * k;
                if (k <= j) {
                    const uint32_t p2 = pk_s[r][j - k];
                    const int ddx = ((int)(p2 & 1u) == t) ? (int)(p2 >> 1) : 0;
                    const int c = ddx * ddx + k2;
                    m = c < m ? c : m;
                }
                if (k <= WW - 1 - j) {
                    const uint32_t p2 = pk_s[r][j + k];
                    const int ddx = ((int)(p2 & 1u) == t) ? (int)(p2 >> 1) : 0;
                    const int c = ddx * ddx + k2;
                    m = c < m ? c : m;
                }
            }
        }
        const float dt = __builtin_amdgcn_sqrtf((float)m);
        float pr = __builtin_amdgcn_rcpf(1.0f + __expf(-xs[r]));
        pr = fminf(fmaxf(pr, 1e-7f), (float)(1.0 - 1e-7));
        v += pr * dt;
    }

    // ---- block reduction (512 threads = 8 waves), one per 2048 px ----
    #pragma unroll
    for (int off = 32; off > 0; off >>= 1)
        v += __shfl_down(v, off);

    const int lane = threadIdx.x & 63;
    const int wid  = threadIdx.x >> 6;
    if (lane == 0) sw[wid] = v;
    __syncthreads();
    if (threadIdx.x == 0) {
        float s = 0.0f;
        #pragma unroll
        for (int ww = 0; ww < 8; ++ww) s += sw[ww];
        partial[g] = s;
    }
}

// ---------------------------------------------------------------------------
// Deterministic final reduction of NGRP partials -> mean
// ---------------------------------------------------------------------------
__global__ __launch_bounds__(512) void finalreduce(
        const float* __restrict__ partial,
        float* __restrict__ out) {
    const float4 q = ((const float4*)partial)[threadIdx.x];   // 512*4 == 2048
    float v = (q.x + q.y) + (q.z + q.w);

    #pragma unroll
    for (int off = 32; off > 0; off >>= 1)
        v += __shfl_down(v, off);

    __shared__ float sw[8];
    const int lane = threadIdx.x & 63;
    const int wid  = threadIdx.x >> 6;
    if (lane == 0) sw[wid] = v;
    __syncthreads();
    if (threadIdx.x == 0) {
        float s = 0.0f;
        #pragma unroll
        for (int ww = 0; ww < 8; ++ww) s += sw[ww];
        out[0] = s * (1.0f / (float)NPIX);
    }
}

extern "C" void kernel_launch(void* const* d_in, const int* in_sizes, int n_in,
                              void* d_out, int out_size, void* d_ws, size_t ws_size,
                              hipStream_t stream) {
    const float* logits  = (const float*)d_in[0];
    const float* targets = (const float*)d_in[1];
    float* out = (float*)d_out;

    // workspace layout: [ vmask u32 NWORDS (512KB) | partial float NGRP (8KB) ]
    uint32_t* vmask = (uint32_t*)d_ws;
    float* partial  = (float*)((char*)d_ws + (size_t)NWORDS * sizeof(uint32_t));

    packbits<<<NWORDS / 2 / 256, 256, 0, stream>>>(targets, vmask);
    fused_row4<<<NGRP, 512, 0, stream>>>(vmask, logits, partial);
    finalreduce<<<1, 512, 0, stream>>>(partial, out);
}

// Round 12
// 21.775 us; speedup vs baseline: 9.5459x; 1.0134x over previous
//
#include <hip/hip_runtime.h>
#include <cstdint>

// Problem constants (from setup_inputs: logits/targets [16,1,512,512] f32)
#define BB 16
#define HH 512
#define WW 512
#define NPIX (BB*HH*WW)          // 4194304
#define WR (HH/32)               // 16 word-rows per image
#define NWORDS (BB*WR*WW)        // 131072 u32 = 512 KB
#define NXCD 8
#define RPB 8                    // rows per block (8-aligned base: p0+7 <= 31)
#define NGRP (BB*HH/RPB)         // 1024 blocks
#define GCHUNK (NGRP/NXCD)       // 128

// ---------------------------------------------------------------------------
// Kernel 0: vertical bit-pack of targets, 2 words per thread via float2 loads.
// vmask[b][w][j] bit r = (targets[b][32w+r][j] > 0.5).  512 KB total.
// ---------------------------------------------------------------------------
__global__ __launch_bounds__(256) void packbits(const float* __restrict__ targets,
                                                uint32_t* __restrict__ vmask) {
    const int flat = blockIdx.x * 256 + threadIdx.x;   // 0..65535
    const int jp = (flat & 255) * 2;                   // even column
    const int w  = (flat >> 8) & (WR - 1);
    const int b  = flat >> 12;
    const float2* base =
        (const float2*)(targets + ((size_t)(b * HH + w * 32)) * WW + jp);
    uint32_t w0 = 0, w1 = 0;
    #pragma unroll
    for (int r = 0; r < 32; ++r) {
        const float2 q = base[r * (WW / 2)];
        w0 |= (q.x > 0.5f ? 1u : 0u) << r;
        w1 |= (q.y > 0.5f ? 1u : 0u) << r;
    }
    ((uint2*)vmask)[flat] = make_uint2(w0, w1);        // 2*flat == b*8192+w*512+jp
}

// ---------------------------------------------------------------------------
// Fused kernel: one block per 8-ROW GROUP (8-aligned rows always share one
// 32-bit word-row), 512 threads = one column each, 8 pixels per thread.
//  Phase 1: the SAME 3 vmask words (self/up/down) serve all 8 rows; per row
//           just shift/ffs/clz on 64-bit windows (exact; word-scan fallback).
//  Phase 2: packed (d<<1)|t in LDS [8][512]; exact pruned row transform,
//           8 independent chains per thread -> deep ILP over LDS latency.
//  Phase 3: p = clip(sigmoid(logit)) via rcp; v += p*sqrt(m); one block
//           reduction per 4096 pixels.
// No atomics/fences (round-7 lesson: device-scope fence chain = 204 us).
// ---------------------------------------------------------------------------
__global__ __launch_bounds__(512) void fused_row8(
        const uint32_t* __restrict__ vmask,
        const float* __restrict__ logits,
        float* __restrict__ partial) {
    const int bid = blockIdx.x;
    const int g   = (bid & (NXCD - 1)) * GCHUNK + (bid >> 3);  // bijective swizzle
    const int b   = g >> 6;                 // 64 groups per image
    const int i0  = (g & 63) << 3;          // first row of the group (8-aligned)
    const int j   = threadIdx.x;
    const int w   = i0 >> 5;                // shared word-row (i0..i0+7 same word)
    const int p0  = i0 & 31;                // in {0,8,16,24}

    __shared__ uint32_t pk_s[RPB][WW];
    __shared__ float    sw[8];

    const uint32_t* vm = vmask + (size_t)b * WR * WW;

    // one word-column triple serves all 8 rows
    const uint32_t Wse = vm[w * WW + j];
    const uint32_t Wup = (w > 0)      ? vm[(w - 1) * WW + j] : 0u;
    const uint32_t Wdn = (w < WR - 1) ? vm[(w + 1) * WW + j] : 0u;

    // logits for the 8 pixels (independent loads, overlap phase 1)
    float xs[RPB];
    #pragma unroll
    for (int r = 0; r < RPB; ++r)
        xs[r] = logits[((size_t)(b * HH + i0 + r)) * WW + j];

    int dpx[RPB], tpx[RPB];
    #pragma unroll
    for (int r = 0; r < RPB; ++r) {
        const int      p  = p0 + r;         // <= 31 always
        const int      i  = i0 + r;
        const int      t  = (int)((Wse >> p) & 1u);
        const uint32_t tm = t ? 0xFFFFFFFFu : 0u;
        const uint32_t Xs = Wse ^ tm;                              // 1 = opposite
        const uint32_t Xu = (w > 0)      ? (Wup ^ tm) : 0u;
        const uint32_t Xd = (w < WR - 1) ? (Wdn ^ tm) : 0u;

        // down window: bit q = row i+1+q (covers rows i+1 .. 32w+63)
        const uint64_t Zd = ((uint64_t)Xs >> (p + 1)) | ((uint64_t)Xd << (31 - p));
        // up window: bit 63 = row i-1, descending (covers rows 32w-32 .. i-1)
        const uint64_t Zu = (((uint64_t)Xs << 32) | (uint64_t)Xu) << (32 - p);

        int dd, du;
        if (Zd) {
            dd = __ffsll((unsigned long long)Zd);      // 1-based == distance
        } else {                                       // essentially never
            dd = 1023;
            for (int ww = w + 2; ww < WR; ++ww) {
                const uint32_t Xw = vm[ww * WW + j] ^ tm;
                if (Xw) { dd = 32 * ww + (__ffs(Xw) - 1) - i; break; }
            }
        }
        if (Zu) {
            du = __clzll((long long)Zu) + 1;
        } else {                                       // essentially never
            du = 1023;
            for (int ww = w - 2; ww >= 0; --ww) {
                const uint32_t Xw = vm[ww * WW + j] ^ tm;
                if (Xw) { du = i - (32 * ww + 31 - __clz((int)Xw)); break; }
            }
        }
        dpx[r] = min(min(dd, du), 1023);
        tpx[r] = t;
        pk_s[r][j] = (uint32_t)((dpx[r] << 1) | t);
    }
    __syncthreads();

    // ---- Phase 2 + 3: eight independent row transforms (ILP) ----
    float v = 0.0f;
    #pragma unroll
    for (int r = 0; r < RPB; ++r) {
        const int t = tpx[r];
        int m = dpx[r] * dpx[r];
        #pragma unroll
        for (int k = 1; k <= 2; ++k) {
            const int jl = j - k, jr = j + k;
            const uint32_t pl = pk_s[r][jl >= 0 ? jl : 0];
            const uint32_t pr = pk_s[r][jr < WW ? jr : (WW - 1)];
            const int dl = ((int)(pl & 1u) == t) ? (int)(pl >> 1) : 0;
            const int dr = ((int)(pr & 1u) == t) ? (int)(pr >> 1) : 0;
            const int cl = (jl >= 0) ? (dl * dl + k * k) : 0x7fffffff;
            const int cr = (jr < WW) ? (dr * dr + k * k) : 0x7fffffff;
            m = min(m, min(cl, cr));
        }
        {
            const int kmaxRow = max(j, WW - 1 - j);
            for (int k = 3; k <= kmaxRow && k * k < m; ++k) {
                const int k2 = k * k;
                if (k <= j) {
                    const uint32_t p2 = pk_s[r][j - k];
                    const int ddx = ((int)(p2 & 1u) == t) ? (int)(p2 >> 1) : 0;
                    const int c = ddx * ddx + k2;
                    m = c < m ? c : m;
                }
                if (k <= WW - 1 - j) {
                    const uint32_t p2 = pk_s[r][j + k];
                    const int ddx = ((int)(p2 & 1u) == t) ? (int)(p2 >> 1) : 0;
                    const int c = ddx * ddx + k2;
                    m = c < m ? c : m;
                }
            }
        }
        const float dt = __builtin_amdgcn_sqrtf((float)m);
        float pr = __builtin_amdgcn_rcpf(1.0f + __expf(-xs[r]));
        pr = fminf(fmaxf(pr, 1e-7f), (float)(1.0 - 1e-7));
        v += pr * dt;
    }

    // ---- block reduction (512 threads = 8 waves), one per 4096 px ----
    #pragma unroll
    for (int off = 32; off > 0; off >>= 1)
        v += __shfl_down(v, off);

    const int lane = threadIdx.x & 63;
    const int wid  = threadIdx.x >> 6;
    if (lane == 0) sw[wid] = v;
    __syncthreads();
    if (threadIdx.x == 0) {
        float s = 0.0f;
        #pragma unroll
        for (int ww = 0; ww < 8; ++ww) s += sw[ww];
        partial[g] = s;
    }
}

// ---------------------------------------------------------------------------
// Deterministic final reduction of NGRP partials -> mean
// ---------------------------------------------------------------------------
__global__ __launch_bounds__(256) void finalreduce(
        const float* __restrict__ partial,
        float* __restrict__ out) {
    const float4 q = ((const float4*)partial)[threadIdx.x];   // 256*4 == 1024
    float v = (q.x + q.y) + (q.z + q.w);

    #pragma unroll
    for (int off = 32; off > 0; off >>= 1)
        v += __shfl_down(v, off);

    __shared__ float sw[4];
    const int lane = threadIdx.x & 63;
    const int wid  = threadIdx.x >> 6;
    if (lane == 0) sw[wid] = v;
    __syncthreads();
    if (threadIdx.x == 0)
        out[0] = ((sw[0] + sw[1]) + (sw[2] + sw[3])) * (1.0f / (float)NPIX);
}

extern "C" void kernel_launch(void* const* d_in, const int* in_sizes, int n_in,
                              void* d_out, int out_size, void* d_ws, size_t ws_size,
                              hipStream_t stream) {
    const float* logits  = (const float*)d_in[0];
    const float* targets = (const float*)d_in[1];
    float* out = (float*)d_out;

    // workspace layout: [ vmask u32 NWORDS (512KB) | partial float NGRP (4KB) ]
    uint32_t* vmask = (uint32_t*)d_ws;
    float* partial  = (float*)((char*)d_ws + (size_t)NWORDS * sizeof(uint32_t));

    packbits<<<NWORDS / 2 / 256, 256, 0, stream>>>(targets, vmask);
    fused_row8<<<NGRP, 512, 0, stream>>>(vmask, logits, partial);
    finalreduce<<<1, 256, 0, stream>>>(partial, out);
}